// Round 15
// baseline (299.650 us; speedup 1.0000x reference)
//
#include <hip/hip_runtime.h>

typedef unsigned short u16;
typedef unsigned int   u32;
typedef unsigned long long u64;

#define BN 8
#define CC 256
#define HW 96
#define NN 9216   // 96*96
#define KK 16

typedef __attribute__((ext_vector_type(8))) short bf16x8;
typedef __attribute__((ext_vector_type(4))) float f32x4;

__device__ __forceinline__ float us2f(u16 u){
  union { u32 i; float f; } v; v.i = ((u32)u) << 16; return v.f;
}
__device__ __forceinline__ u16 f2us(float f){
  __bf16 h = (__bf16)f;                       // native RNE convert
  return __builtin_bit_cast(unsigned short, h);
}
__device__ __forceinline__ float lrelu(float v){ return v >= 0.f ? v : 0.001f*v; }

// LDS swizzle for [64 n][256 c] bf16 tile (512B rows), 16B granules
__device__ __forceinline__ u32 swz7(int n, int c){
  return (u32)(n*512 + ((((c>>3) ^ (n&31)) & 31)<<4) + ((c&7)<<1));
}
// LDS swizzle for [col][96 k] bf16 tile padded to 256B rows
__device__ __forceinline__ u32 swz8(int col, int k){
  return (u32)(col*256 + ((((k>>3) ^ (col&15)) & 15)<<4) + ((k&7)<<1));
}

// ---------------- K1: F = w_f.x ; Bm ; AM ; xf ; Ff — 512 thr, 2-way c-split ----------------
__global__ __launch_bounds__(512) void k1_fx(
    const float* __restrict__ x, const float* __restrict__ w_f, const float* __restrict__ w_a2b,
    float* __restrict__ F, float* __restrict__ AM, float* __restrict__ Bm,
    u16* __restrict__ xf, u16* __restrict__ Ff)
{
  __shared__ float wf[CC][KK];   // 16 KB
  __shared__ float wa[CC];       // 1 KB
  __shared__ float pa[256][KK];  // 16 KB partial a0 (half 1)
  __shared__ float ps[256], pm[256], pb[256];   // 3 KB
  int t = threadIdx.x;
  for (int i = t; i < KK*CC; i += 512) wf[i & 255][i >> 8] = w_f[i];
  if (t < CC) wa[t] = w_a2b[t];
  __syncthreads();
  int half = t >> 8, tp = t & 255;
  int pid = blockIdx.x*256 + tp;
  int b = pid / NN;
  int n = pid % NN;
  const float* xp = x + (size_t)b*CC*NN + n;
  float a0[KK];
  #pragma unroll
  for (int k=0;k<KK;k++) a0[k]=0.f;
  float s0=0.f, m0=-3e38f, b0=0.f;
  int nt = n >> 4, lnn = n & 15;
  u16* xfb = xf + ((size_t)(b*576 + nt)*8)*512;   // ks*512 + lane*8 + e  (u16 units)
  int cb0 = half*128;
  #pragma unroll 2
  for (int c8=0; c8<16; ++c8){
    int cb = cb0 + c8*8;
    float v[8];
    #pragma unroll
    for (int e=0;e<8;e++) v[e] = xp[(size_t)(cb+e)*NN];
    union { u16 h[8]; uint4 u; } pk;
    #pragma unroll
    for (int e=0;e<8;e++){
      float vv = v[e];
      s0 += vv;
      m0 = fmaxf(m0, vv);
      b0 = fmaf(wa[cb+e], vv, b0);
      const float* wr = wf[cb+e];
      #pragma unroll
      for (int k=0;k<KK;k++) a0[k] = fmaf(wr[k], vv, a0[k]);
      pk.h[e] = f2us(vv);
    }
    int ks = cb >> 5, lkq = (cb >> 3) & 3;
    *reinterpret_cast<uint4*>(xfb + ((size_t)ks*64 + lkq*16 + lnn)*8) = pk.u;
  }
  if (half){
    #pragma unroll
    for (int k=0;k<KK;k++) pa[tp][k] = a0[k];
    ps[tp] = s0; pm[tp] = m0; pb[tp] = b0;
  }
  __syncthreads();
  if (!half){
    #pragma unroll
    for (int k=0;k<KK;k++) a0[k] += pa[tp][k];
    s0 += ps[tp]; m0 = fmaxf(m0, pm[tp]); b0 += pb[tp];
    float* Fp = F + (size_t)b*KK*NN + n;
    #pragma unroll
    for (int k=0;k<KK;k++) Fp[(size_t)k*NN] = a0[k];
    // Ff: B-frag layout, K=16 padded to 32 (lk 2,3 zero)
    u16* ffb = Ff + (size_t)(b*576 + nt)*512;
    union { u16 h[8]; uint4 u; } pk2;
    #pragma unroll
    for (int lkq=0; lkq<2; lkq++){
      #pragma unroll
      for (int e=0;e<8;e++) pk2.h[e] = f2us(a0[lkq*8+e]);
      *reinterpret_cast<uint4*>(ffb + ((size_t)lkq*16 + lnn)*8) = pk2.u;
    }
    uint4 z; z.x=z.y=z.z=z.w=0u;
    *reinterpret_cast<uint4*>(ffb + ((size_t)2*16 + lnn)*8) = z;
    *reinterpret_cast<uint4*>(ffb + ((size_t)3*16 + lnn)*8) = z;
    AM[(size_t)b*2*NN + n] = s0*(1.f/256.f);
    AM[(size_t)b*2*NN + NN + n] = m0;
    Bm[(size_t)b*NN + n] = lrelu(b0);
  }
}

// ---------------- K2: G[b,k,c] = sum_n F[b,k,n]*x[b,c,n]  (4 c per block) ----------------
__global__ __launch_bounds__(256) void k2_g(
    const float* __restrict__ x, const float* __restrict__ F, float* __restrict__ G)
{
  int b = blockIdx.x >> 6;
  int c0 = (blockIdx.x & 63) * 4;
  int t = threadIdx.x;
  const float* Fp = F + (size_t)b*KK*NN;
  const float* xp = x + ((size_t)b*CC + c0)*NN;
  float acc[KK][4];
  #pragma unroll
  for (int k=0;k<KK;k++){ acc[k][0]=acc[k][1]=acc[k][2]=acc[k][3]=0.f; }
  for (int n = t; n < NN; n += 256){
    float xv0 = xp[n];
    float xv1 = xp[(size_t)NN + n];
    float xv2 = xp[(size_t)2*NN + n];
    float xv3 = xp[(size_t)3*NN + n];
    #pragma unroll
    for (int k=0;k<KK;k++){
      float fv = Fp[(size_t)k*NN + n];
      acc[k][0] = fmaf(fv, xv0, acc[k][0]);
      acc[k][1] = fmaf(fv, xv1, acc[k][1]);
      acc[k][2] = fmaf(fv, xv2, acc[k][2]);
      acc[k][3] = fmaf(fv, xv3, acc[k][3]);
    }
  }
  #pragma unroll
  for (int k=0;k<KK;k++){
    #pragma unroll
    for (int i=0;i<4;i++){
      float v = acc[k][i];
      for (int off=32; off>0; off>>=1) v += __shfl_down(v, off);
      acc[k][i] = v;
    }
  }
  __shared__ float part[4][KK][4];
  int lane = t & 63, wv = t >> 6;
  if (lane == 0){
    #pragma unroll
    for (int k=0;k<KK;k++){ part[wv][k][0]=acc[k][0]; part[wv][k][1]=acc[k][1];
                            part[wv][k][2]=acc[k][2]; part[wv][k][3]=acc[k][3]; }
  }
  __syncthreads();
  if (t < 64){
    int k = t >> 2, i = t & 3;
    float s = part[0][k][i] + part[1][k][i] + part[2][k][i] + part[3][k][i];
    G[((size_t)b*KK + k)*CC + c0 + i] = s;
  }
}

// ---------------- K3: S = softmax_c(G) ; WS = w_beta.S^T packed as MFMA A-frags (K=16 pad 32) ----------------
__global__ __launch_bounds__(256) void k3_smws(
    const float* __restrict__ G, const float* __restrict__ w_beta, u16* __restrict__ wspk)
{
  int b = blockIdx.x, t = threadIdx.x;
  __shared__ float sl[KK][CC];
  for (int k=0;k<KK;k++) sl[k][t] = G[((size_t)b*KK + k)*CC + t];
  __syncthreads();
  int lane = t & 63, wv = t >> 6;
  for (int r=0;r<4;r++){
    int k = wv*4 + r;
    float v0 = sl[k][lane], v1 = sl[k][lane+64], v2 = sl[k][lane+128], v3 = sl[k][lane+192];
    float m = fmaxf(fmaxf(v0,v1), fmaxf(v2,v3));
    for (int off=32; off>0; off>>=1) m = fmaxf(m, __shfl_xor(m, off));
    float e0=__expf(v0-m), e1=__expf(v1-m), e2=__expf(v2-m), e3=__expf(v3-m);
    float s = e0+e1+e2+e3;
    for (int off=32; off>0; off>>=1) s += __shfl_xor(s, off);
    float inv = 1.f/s;
    sl[k][lane]=e0*inv; sl[k][lane+64]=e1*inv; sl[k][lane+128]=e2*inv; sl[k][lane+192]=e3*inv;
  }
  __syncthreads();
  const float* wb = w_beta + (size_t)t*CC;
  float acc[KK];
  #pragma unroll
  for (int k=0;k<KK;k++) acc[k]=0.f;
  for (int c=0;c<CC;c++){
    float w = wb[c];
    #pragma unroll
    for (int k=0;k<KK;k++) acc[k] = fmaf(w, sl[k][c], acc[k]);
  }
  int ot = t >> 4, lo = t & 15;
  union { u16 h[8]; uint4 u; } pk;
  #pragma unroll
  for (int lkq=0; lkq<2; lkq++){
    #pragma unroll
    for (int e=0;e<8;e++) pk.h[e] = f2us(acc[lkq*8+e]);
    *reinterpret_cast<uint4*>(wspk + ((size_t)(b*16 + ot)*64 + lkq*16 + lo)*8) = pk.u;
  }
  uint4 z; z.x=z.y=z.z=z.w=0u;
  *reinterpret_cast<uint4*>(wspk + ((size_t)(b*16 + ot)*64 + 2*16 + lo)*8) = z;
  *reinterpret_cast<uint4*>(wspk + ((size_t)(b*16 + ot)*64 + 3*16 + lo)*8) = z;
}

// ---------------- K5: spatial convs -> F4, Cm ----------------
__global__ __launch_bounds__(256) void k5_conv(
    const float* __restrict__ AM, const float* __restrict__ w1, const float* __restrict__ w3,
    const float* __restrict__ w5, const float* __restrict__ w7, const float* __restrict__ wf2c,
    float* __restrict__ F4, float* __restrict__ Cm)
{
  __shared__ float w3l[18], w5l[50], w7l[98], w1l[2], wcl[4];
  int t = threadIdx.x;
  if (t < 2)  w1l[t] = w1[t];
  if (t < 18) w3l[t] = w3[t];
  if (t < 50) w5l[t] = w5[t];
  if (t < 98) w7l[t] = w7[t];
  if (t < 4)  wcl[t] = wf2c[t];
  __syncthreads();
  int gid = blockIdx.x*256 + t;
  int b = gid / NN, n = gid % NN;
  int h = n / HW, w = n % HW;
  const float* am = AM + (size_t)b*2*NN;
  float a0 = am[n], a1 = am[NN + n];
  float s1v = lrelu(a0*w1l[0] + a1*w1l[1]);
  float s3v=0.f, s5v=0.f, s7v=0.f;
  for (int p=-3;p<=3;p++){
    int hh = h + p;
    if (hh < 0 || hh >= HW) continue;
    for (int q=-3;q<=3;q++){
      int ww = w + q;
      if (ww < 0 || ww >= HW) continue;
      float v0 = am[hh*HW+ww], v1 = am[NN + hh*HW + ww];
      s7v += v0*w7l[(p+3)*7 + (q+3)] + v1*w7l[49 + (p+3)*7 + (q+3)];
      if (p>=-2 && p<=2 && q>=-2 && q<=2)
        s5v += v0*w5l[(p+2)*5 + (q+2)] + v1*w5l[25 + (p+2)*5 + (q+2)];
      if (p>=-1 && p<=1 && q>=-1 && q<=1)
        s3v += v0*w3l[(p+1)*3 + (q+1)] + v1*w3l[9 + (p+1)*3 + (q+1)];
    }
  }
  s3v = lrelu(s3v); s5v = lrelu(s5v); s7v = lrelu(s7v);
  float* f4p = F4 + (size_t)b*4*NN + n;
  f4p[0] = s1v; f4p[NN] = s3v; f4p[2*(size_t)NN] = s5v; f4p[3*(size_t)NN] = s7v;
  Cm[(size_t)b*NN + n] = lrelu(s1v*wcl[0] + s3v*wcl[1] + s5v*wcl[2] + s7v*wcl[3]);
}

// ---------------- K6AB: T rows + softmax + spk pack, 64 blocks (8 b x 8 h-groups of 12) ----------------
__global__ __launch_bounds__(256) void k6ab(
    const float* __restrict__ Bm, const float* __restrict__ Cm, u16* __restrict__ spk)
{
  __shared__ float Cl[NN];        // 36 KB
  __shared__ float Tl[12][96];    // 4.5 KB
  int t = threadIdx.x;
  int b = blockIdx.x >> 3;
  int hg = blockIdx.x & 7;
  for (int i=t; i<NN/4; i+=256)
    *reinterpret_cast<float4*>(&Cl[i*4]) = *reinterpret_cast<const float4*>(&Cm[(size_t)b*NN + i*4]);
  __syncthreads();
  const float* bp = Bm + (size_t)b*NN + (size_t)hg*12*96;
  for (int g=0; g<2; ++g){
    int idx = g*256 + t;
    if (idx < 288){
      int hr = idx/24, k0 = (idx%24)*4;
      const float* brow = bp + hr*96;
      float a0=0.f,a1=0.f,a2=0.f,a3=0.f;
      for (int w2=0; w2<96; ++w2){
        float bv = brow[w2];
        float4 cv = *reinterpret_cast<const float4*>(&Cl[w2*96 + k0]);
        a0=fmaf(bv,cv.x,a0); a1=fmaf(bv,cv.y,a1); a2=fmaf(bv,cv.z,a2); a3=fmaf(bv,cv.w,a3);
      }
      Tl[hr][k0]=a0; Tl[hr][k0+1]=a1; Tl[hr][k0+2]=a2; Tl[hr][k0+3]=a3;
    }
  }
  __syncthreads();
  if (t < 12){
    int h = hg*12 + t;
    float m = -3e38f;
    for (int k=0;k<96;k++) m = fmaxf(m, Tl[t][k]);
    float s = 0.f;
    for (int k=0;k<96;k++) s += __expf(Tl[t][k]-m);
    float inv = 1.f/s;
    int mf = h >> 4;
    for (int g=0; g<12; g++){
      int ks = g >> 2, lk = g & 3;
      union { u16 hh[8]; uint4 u; } pk;
      #pragma unroll
      for (int e=0;e<8;e++) pk.hh[e] = f2us(__expf(Tl[t][g*8+e]-m)*inv);
      *reinterpret_cast<uint4*>(spk + ((size_t)(((b*6 + mf)*3 + ks)*64) + lk*16 + (h&15))*8) = pk.u;
    }
  }
}

// ---------------- KW: pack w_h / w_m / w_hm (256x512) and w_e (256x256) into bf16 A-frag order ----------------
__global__ __launch_bounds__(256) void kw_pack(
    const float* __restrict__ w_h, const float* __restrict__ w_m,
    const float* __restrict__ w_hm, const float* __restrict__ w_e,
    u16* __restrict__ wpk, u16* __restrict__ wpkE)
{
  int gid = blockIdx.x*256 + threadIdx.x;   // 57344
  if (gid < 49152){
    int mat = gid >> 14;
    int r = gid & 16383;
    int ot = r >> 10;
    int ks = (r >> 6) & 15;
    int l  = r & 63;
    const float* W = (mat==0) ? w_h : ((mat==1) ? w_m : w_hm);
    int o = ot*16 + (l & 15);
    int c = ks*32 + (l >> 4)*8;
    const float* src = W + (size_t)o*512 + c;
    union { u16 h[8]; uint4 u; } pk;
    #pragma unroll
    for (int e=0;e<8;e++) pk.h[e] = f2us(src[e]);
    *reinterpret_cast<uint4*>(wpk + (size_t)gid*8) = pk.u;
  } else {
    int r = gid - 49152;                    // 8192 frags for w_e (K=256)
    int ot = r >> 9;
    int ks = (r >> 6) & 7;
    int l  = r & 63;
    int o = ot*16 + (l & 15);
    int c = ks*32 + (l >> 4)*8;
    const float* src = w_e + (size_t)o*256 + c;
    union { u16 h[8]; uint4 u; } pk;
    #pragma unroll
    for (int e=0;e<8;e++) pk.h[e] = f2us(src[e]);
    *reinterpret_cast<uint4*>(wpkE + (size_t)r*8) = pk.u;
  }
}

// ---------------- K7M: WD = w_e . lrelu(w_f2d . F4) — MFMA, M=256 N=64 K=256 per block ----------------
__global__ __launch_bounds__(256) void k7m(
    const float* __restrict__ F4, const float* __restrict__ w_f2d,
    const u16* __restrict__ wpkE, u16* __restrict__ WD)
{
  __shared__ uint4 sm4[2048];               // 32 KB: [64 n][256 c] bf16 swizzled
  char* sm = reinterpret_cast<char*>(sm4);
  int t = threadIdx.x;
  int b = blockIdx.x / 144;
  int n0 = (blockIdx.x % 144) * 64;
  int n = t & 63, cg = t >> 6;
  float f0 = F4[((size_t)b*4+0)*NN + n0 + n];
  float f1 = F4[((size_t)b*4+1)*NN + n0 + n];
  float f2 = F4[((size_t)b*4+2)*NN + n0 + n];
  float f3 = F4[((size_t)b*4+3)*NN + n0 + n];
  for (int c8 = 0; c8 < 8; ++c8){
    int c = cg*64 + c8*8;
    union { u16 h[8]; uint4 u; } pk;
    #pragma unroll
    for (int e=0;e<8;e++){
      const float* wfp = w_f2d + (size_t)(c+e)*4;
      pk.h[e] = f2us(lrelu(fmaf(wfp[0],f0, fmaf(wfp[1],f1, fmaf(wfp[2],f2, wfp[3]*f3)))));
    }
    *reinterpret_cast<uint4*>(sm + swz7(n, c)) = pk.u;
  }
  __syncthreads();
  int w = t >> 6, l = t & 63, ln = l & 15, lk = l >> 4;
  f32x4 acc[4][4];
  #pragma unroll
  for (int i=0;i<4;i++){ acc[i][0]=0.f; acc[i][1]=0.f; acc[i][2]=0.f; acc[i][3]=0.f; }
  for (int ks=0; ks<8; ++ks){
    bf16x8 bfr[4];
    #pragma unroll
    for (int nf=0; nf<4; nf++)
      bfr[nf] = *reinterpret_cast<const bf16x8*>(sm + swz7(nf*16 + ln, ks*32 + lk*8));
    #pragma unroll
    for (int mf=0; mf<4; mf++){
      bf16x8 afr = *reinterpret_cast<const bf16x8*>(wpkE + ((size_t)((w*4+mf)*8 + ks)*64 + l)*8);
      #pragma unroll
      for (int nf=0; nf<4; nf++)
        acc[mf][nf] = __builtin_amdgcn_mfma_f32_16x16x32_bf16(afr, bfr[nf], acc[mf][nf], 0,0,0);
    }
  }
  #pragma unroll
  for (int mf=0; mf<4; mf++){
    #pragma unroll
    for (int nf=0; nf<4; nf++){
      #pragma unroll
      for (int r=0;r<4;r++){
        int o = (w*4+mf)*16 + lk*4 + r;
        WD[((size_t)b*CC + o)*NN + n0 + nf*16 + ln] = f2us(acc[mf][nf][r]);
      }
    }
  }
}

// ---------------- K8M: P = Ssp x WD — MFMA, M=96(h) N=192(2o x 96w) K=96 per block ----------------
__global__ __launch_bounds__(256) void k8m(
    const u16* __restrict__ WD, const u16* __restrict__ spk, u16* __restrict__ P)
{
  __shared__ uint4 sm4[3072];               // 48 KB: [192 col][128 k-pad] bf16 swizzled
  char* sm = reinterpret_cast<char*>(sm4);
  int t = threadIdx.x;
  int b = blockIdx.x >> 7;
  int o0 = (blockIdx.x & 127) * 2;
  for (int it=0; it<9; ++it){
    int s = it*256 + t;                     // 0..2303
    int w16 = s % 12;
    int k   = (s / 12) % 96;
    int oi  = s / 1152;
    union { u16 h[8]; uint4 u; } v;
    v.u = *reinterpret_cast<const uint4*>(WD + ((size_t)b*CC + o0+oi)*NN + k*96 + w16*8);
    #pragma unroll
    for (int e=0;e<8;e++){
      int col = oi*96 + w16*8 + e;
      *reinterpret_cast<u16*>(sm + swz8(col, k)) = v.h[e];
    }
  }
  __syncthreads();
  int w = t >> 6, l = t & 63, ln = l & 15, lk = l >> 4;
  f32x4 acc[6][3];
  #pragma unroll
  for (int i=0;i<6;i++){ acc[i][0]=0.f; acc[i][1]=0.f; acc[i][2]=0.f; }
  for (int ks=0; ks<3; ++ks){
    bf16x8 bfr[3];
    #pragma unroll
    for (int j=0;j<3;j++){
      int col = (w*3 + j)*16 + ln;
      bfr[j] = *reinterpret_cast<const bf16x8*>(sm + swz8(col, ks*32 + lk*8));
    }
    #pragma unroll
    for (int mf=0; mf<6; mf++){
      bf16x8 afr = *reinterpret_cast<const bf16x8*>(spk + ((size_t)(((b*6 + mf)*3 + ks)*64) + l)*8);
      #pragma unroll
      for (int j=0;j<3;j++)
        acc[mf][j] = __builtin_amdgcn_mfma_f32_16x16x32_bf16(afr, bfr[j], acc[mf][j], 0,0,0);
    }
  }
  #pragma unroll
  for (int j=0;j<3;j++){
    int col = (w*3 + j)*16 + ln;
    int oi = (col >= 96) ? 1 : 0;
    int ww = col - 96*oi;
    u16* op = P + ((size_t)b*CC + o0+oi)*NN + ww;
    #pragma unroll
    for (int mf=0; mf<6; mf++){
      #pragma unroll
      for (int r=0;r<4;r++){
        int h = mf*16 + lk*4 + r;
        op[(size_t)h*96] = f2us(acc[mf][j][r]);
      }
    }
  }
}

// ---------------- K8T: o2t = P^T(B-frag) + x — LDS tile transpose + residual ----------------
#define TP 72
__global__ __launch_bounds__(256) void k8t(
    const u16* __restrict__ P, const u16* __restrict__ xf, u16* __restrict__ o2t)
{
  __shared__ u16 tl[256*TP];                // [256 o][72 n-pitch] = 36 KB
  int t = threadIdx.x;
  int b = blockIdx.x / 144;
  int tile = blockIdx.x % 144;
  int n0 = tile * 64;
  for (int it=0; it<8; ++it){
    int o = it*32 + (t >> 3);
    int nb = t & 7;
    uint4 v = *reinterpret_cast<const uint4*>(P + ((size_t)b*CC + o)*NN + n0 + nb*8);
    *reinterpret_cast<uint4*>(&tl[o*TP + nb*8]) = v;
  }
  __syncthreads();
  for (int it=0; it<8; ++it){
    int g = it*256 + t;                     // 0..2047
    int nt_loc = g >> 9;
    int ks = (g >> 6) & 7;
    int lane = g & 63;
    int lkq = lane >> 4, lnn = lane & 15;
    int ob = ks*32 + lkq*8;
    int n_loc = nt_loc*16 + lnn;
    union { u16 h[8]; uint4 u; } gr;
    #pragma unroll
    for (int e=0;e<8;e++) gr.h[e] = tl[(ob+e)*TP + n_loc];
    size_t fo = (((size_t)(b*576 + tile*4 + nt_loc)*8 + ks)*64 + lkq*16 + lnn)*8;
    uint4 xv = *reinterpret_cast<const uint4*>(xf + fo);
    const u32* xp2 = reinterpret_cast<const u32*>(&xv);
    union { u16 h[8]; uint4 u; } res;
    #pragma unroll
    for (int q=0;q<4;q++){
      u32 xw = xp2[q];
      res.h[2*q+0] = f2us(us2f(gr.h[2*q+0]) + us2f((u16)(xw & 0xffffu)));
      res.h[2*q+1] = f2us(us2f(gr.h[2*q+1]) + us2f((u16)(xw >> 16)));
    }
    *reinterpret_cast<uint4*>(o2t + fo) = res.u;
  }
}

// ---------------- K910: out1 -> Hh -> M -> H_M fused; M via global scratch; 32 KB LDS ----------------
__global__ __launch_bounds__(512) void k910(
    const u16* __restrict__ o2t, const u16* __restrict__ xf,
    const u16* __restrict__ Ff, const u16* __restrict__ wspk,
    const u16* __restrict__ wpkH, const u16* __restrict__ wpkM,
    const u16* __restrict__ wpkHM, u16* __restrict__ Mg, float* __restrict__ out)
{
  __shared__ uint4 sm4[2048];   // 32 KB: out1 -> Hh
  char* sm = reinterpret_cast<char*>(sm4);
  int t = threadIdx.x;
  int b = blockIdx.x / 144;
  int tile = blockIdx.x % 144;
  int n0 = tile * 64;
  int w = t >> 6, l = t & 63, ln = l & 15, lk = l >> 4;   // 8 waves
  // ---- ph0: out1 = WS.F + x (K=16 zero-padded to 32), write to LDS ----
  {
    bf16x8 fb[4];
    #pragma unroll
    for (int nf=0; nf<4; nf++)
      fb[nf] = *reinterpret_cast<const bf16x8*>(Ff + (size_t)(b*576 + tile*4 + nf)*512 + (size_t)l*8);
    #pragma unroll
    for (int mf=0; mf<2; mf++){
      bf16x8 afr = *reinterpret_cast<const bf16x8*>(wspk + ((size_t)(b*16 + w*2 + mf)*64 + l)*8);
      int obase = w*32 + mf*16 + lk*4;
      #pragma unroll
      for (int nf=0; nf<4; nf++){
        f32x4 zz = {0.f,0.f,0.f,0.f};
        f32x4 a1 = __builtin_amdgcn_mfma_f32_16x16x32_bf16(afr, fb[nf], zz, 0,0,0);
        int n = nf*16 + ln;
        int nt = tile*4 + nf;
        u64 xv4 = *reinterpret_cast<const u64*>(
            xf + (((size_t)(b*576 + nt)*8 + (obase>>5))*64 + ((obase>>3)&3)*16 + ln)*8 + (obase&7));
        union { u16 h[4]; u64 u; } pk;
        #pragma unroll
        for (int r=0;r<4;r++)
          pk.h[r] = f2us(a1[r] + us2f((u16)(xv4 >> (16*r))));
        *reinterpret_cast<u64*>(sm + swz7(n, obase)) = pk.u;
      }
    }
  }
  __syncthreads();
  f32x4 acc[2][4];
  // ---- ph1: Hh = lrelu(w_h.[out1; out2]) — out1 from LDS, o2 frags from global ----
  #pragma unroll
  for (int i=0;i<2;i++){ acc[i][0]=0.f; acc[i][1]=0.f; acc[i][2]=0.f; acc[i][3]=0.f; }
  #pragma unroll 2
  for (int ks=0; ks<16; ++ks){
    bf16x8 bfr[4];
    if (ks < 8){
      int c = ks*32 + lk*8;
      #pragma unroll
      for (int nf=0; nf<4; nf++)
        bfr[nf] = *reinterpret_cast<const bf16x8*>(sm + swz7(nf*16 + ln, c));
    } else {
      #pragma unroll
      for (int nf=0; nf<4; nf++)
        bfr[nf] = *reinterpret_cast<const bf16x8*>(o2t + (((size_t)(b*576 + tile*4 + nf)*8 + (ks-8))*64 + l)*8);
    }
    #pragma unroll
    for (int mf=0; mf<2; mf++){
      bf16x8 afr = *reinterpret_cast<const bf16x8*>(wpkH + ((size_t)((w*2+mf)*16 + ks)*64 + l)*8);
      #pragma unroll
      for (int nf=0; nf<4; nf++)
        acc[mf][nf] = __builtin_amdgcn_mfma_f32_16x16x32_bf16(afr, bfr[nf], acc[mf][nf], 0,0,0);
    }
  }
  __syncthreads();           // all ph1 reads of LDS complete
  // Hh -> LDS (overwrite out1)
  #pragma unroll
  for (int mf=0; mf<2; mf++){
    int obase = w*32 + mf*16 + lk*4;
    #pragma unroll
    for (int nf=0; nf<4; nf++){
      int n = nf*16 + ln;
      union { u16 h[4]; u64 u; } pk;
      #pragma unroll
      for (int r=0;r<4;r++) pk.h[r] = f2us(lrelu(acc[mf][nf][r]));
      *reinterpret_cast<u64*>(sm + swz7(n, obase)) = pk.u;
    }
  }
  __syncthreads();
  // ---- ph2a: M = sigmoid(w_m.[Hh; x]) — x frags from global; M -> Mg (global, B-frag layout) ----
  #pragma unroll
  for (int i=0;i<2;i++){ acc[i][0]=0.f; acc[i][1]=0.f; acc[i][2]=0.f; acc[i][3]=0.f; }
  #pragma unroll 2
  for (int ks=0; ks<16; ++ks){
    bf16x8 bfr[4];
    if (ks < 8){
      int c = ks*32 + lk*8;
      #pragma unroll
      for (int nf=0; nf<4; nf++)
        bfr[nf] = *reinterpret_cast<const bf16x8*>(sm + swz7(nf*16 + ln, c));
    } else {
      #pragma unroll
      for (int nf=0; nf<4; nf++)
        bfr[nf] = *reinterpret_cast<const bf16x8*>(xf + (((size_t)(b*576 + tile*4 + nf)*8 + (ks-8))*64 + l)*8);
    }
    #pragma unroll
    for (int mf=0; mf<2; mf++){
      bf16x8 afr = *reinterpret_cast<const bf16x8*>(wpkM + ((size_t)((w*2+mf)*16 + ks)*64 + l)*8);
      #pragma unroll
      for (int nf=0; nf<4; nf++)
        acc[mf][nf] = __builtin_amdgcn_mfma_f32_16x16x32_bf16(afr, bfr[nf], acc[mf][nf], 0,0,0);
    }
  }
  #pragma unroll
  for (int mf=0; mf<2; mf++){
    int obase = w*32 + mf*16 + lk*4;
    #pragma unroll
    for (int nf=0; nf<4; nf++){
      int nt = tile*4 + nf;
      union { u16 h[4]; u64 u; } pk;
      #pragma unroll
      for (int r=0;r<4;r++) pk.h[r] = f2us(1.f/(1.f + __expf(-acc[mf][nf][r])));
      *reinterpret_cast<u64*>(
          Mg + (((size_t)(b*576 + nt)*8 + (obase>>5))*64 + ((obase>>3)&3)*16 + ln)*8 + (obase&7)) = pk.u;
    }
  }
  __threadfence_block();
  __syncthreads();
  // ---- ph2b: out = lrelu(w_hm.[Hh; M]) — Hh from LDS, M frags from Mg ----
  #pragma unroll
  for (int i=0;i<2;i++){ acc[i][0]=0.f; acc[i][1]=0.f; acc[i][2]=0.f; acc[i][3]=0.f; }
  #pragma unroll 2
  for (int ks=0; ks<16; ++ks){
    bf16x8 bfr[4];
    if (ks < 8){
      int c = ks*32 + lk*8;
      #pragma unroll
      for (int nf=0; nf<4; nf++)
        bfr[nf] = *reinterpret_cast<const bf16x8*>(sm + swz7(nf*16 + ln, c));
    } else {
      #pragma unroll
      for (int nf=0; nf<4; nf++)
        bfr[nf] = *reinterpret_cast<const bf16x8*>(Mg + (((size_t)(b*576 + tile*4 + nf)*8 + (ks-8))*64 + l)*8);
    }
    #pragma unroll
    for (int mf=0; mf<2; mf++){
      bf16x8 afr = *reinterpret_cast<const bf16x8*>(wpkHM + ((size_t)((w*2+mf)*16 + ks)*64 + l)*8);
      #pragma unroll
      for (int nf=0; nf<4; nf++)
        acc[mf][nf] = __builtin_amdgcn_mfma_f32_16x16x32_bf16(afr, bfr[nf], acc[mf][nf], 0,0,0);
    }
  }
  #pragma unroll
  for (int mf=0; mf<2; mf++){
    #pragma unroll
    for (int nf=0; nf<4; nf++){
      #pragma unroll
      for (int r=0;r<4;r++){
        int o = w*32 + mf*16 + lk*4 + r;
        out[((size_t)b*CC + o)*NN + n0 + nf*16 + ln] = lrelu(acc[mf][nf][r]);
      }
    }
  }
}

extern "C" void kernel_launch(void* const* d_in, const int* in_sizes, int n_in,
                              void* d_out, int out_size, void* d_ws, size_t ws_size,
                              hipStream_t stream)
{
  const float* x     = (const float*)d_in[0];
  const float* w_f   = (const float*)d_in[1];
  const float* w_beta= (const float*)d_in[2];
  const float* w1    = (const float*)d_in[3];
  const float* w3    = (const float*)d_in[4];
  const float* w5    = (const float*)d_in[5];
  const float* w7    = (const float*)d_in[6];
  const float* w_a2b = (const float*)d_in[7];
  const float* w_f2c = (const float*)d_in[8];
  const float* w_f2d = (const float*)d_in[9];
  const float* w_e   = (const float*)d_in[10];
  const float* w_h   = (const float*)d_in[11];
  const float* w_m   = (const float*)d_in[12];
  const float* w_hm  = (const float*)d_in[13];

  char* ws = (char*)d_ws;
  size_t off = 0;
  auto alloc = [&](size_t bytes) -> void* {
    void* p = ws + off; off += (bytes + 255) & ~(size_t)255; return p;
  };
  float* F    = (float*)alloc(sizeof(float)*(size_t)BN*KK*NN);
  float* AMb  = (float*)alloc(sizeof(float)*(size_t)BN*2*NN);
  float* Bmv  = (float*)alloc(sizeof(float)*(size_t)BN*NN);
  float* Cmv  = (float*)alloc(sizeof(float)*(size_t)BN*NN);
  float* F4   = (float*)alloc(sizeof(float)*(size_t)BN*4*NN);
  float* G    = (float*)alloc(sizeof(float)*(size_t)BN*KK*CC);
  u16*   spk  = (u16*)alloc(sizeof(u16)*(size_t)BN*NN);           // packed softmax S
  u16*   WD   = (u16*)alloc(sizeof(u16)*(size_t)BN*CC*NN);
  u16*   Pm   = (u16*)alloc(sizeof(u16)*(size_t)BN*CC*NN);        // Ssp x WD, row-major
  u16*   o2t  = (u16*)alloc(sizeof(u16)*(size_t)BN*CC*NN);        // out2 in B-frag layout
  u16*   xf   = (u16*)alloc(sizeof(u16)*(size_t)BN*CC*NN);        // x bf16 B-frag layout
  u16*   Mg   = (u16*)alloc(sizeof(u16)*(size_t)BN*CC*NN);        // M in B-frag layout
  u16*   Ff   = (u16*)alloc(sizeof(u16)*(size_t)BN*576*512);      // F bf16 B-frags (K pad 32)
  u16*   wpk  = (u16*)alloc(sizeof(u16)*(size_t)3*16384*8);       // packed w_h/w_m/w_hm
  u16*   wpkE = (u16*)alloc(sizeof(u16)*(size_t)8192*8);          // packed w_e
  u16*   wspk = (u16*)alloc(sizeof(u16)*(size_t)BN*16*64*8);      // packed WS A-frags
  (void)ws_size; (void)in_sizes; (void)n_in; (void)out_size;

  u16* wpkH  = wpk;
  u16* wpkM  = wpk + (size_t)16384*8;
  u16* wpkHM = wpk + (size_t)2*16384*8;

  kw_pack <<<224, 256, 0, stream>>>(w_h, w_m, w_hm, w_e, wpk, wpkE);
  k1_fx   <<<288, 512, 0, stream>>>(x, w_f, w_a2b, F, AMb, Bmv, xf, Ff);
  k2_g    <<<512, 256, 0, stream>>>(x, F, G);
  k3_smws <<<8,   256, 0, stream>>>(G, w_beta, wspk);
  k5_conv <<<288, 256, 0, stream>>>(AMb, w1, w3, w5, w7, w_f2c, F4, Cmv);
  k6ab    <<<64,  256, 0, stream>>>(Bmv, Cmv, spk);
  k7m     <<<1152,256, 0, stream>>>(F4, w_f2d, wpkE, WD);
  k8m     <<<1024,256, 0, stream>>>(WD, spk, Pm);
  k8t     <<<1152,256, 0, stream>>>(Pm, xf, o2t);
  k910    <<<1152,512, 0, stream>>>(o2t, xf, Ff, wspk, wpkH, wpkM, wpkHM, Mg, (float*)d_out);
}

// Round 16
// 268.089 us; speedup vs baseline: 1.1177x; 1.1177x over previous
//
#include <hip/hip_runtime.h>

typedef unsigned short u16;
typedef unsigned int   u32;
typedef unsigned long long u64;

#define BN 8
#define CC 256
#define HW 96
#define NN 9216   // 96*96
#define KK 16

typedef __attribute__((ext_vector_type(8))) short bf16x8;
typedef __attribute__((ext_vector_type(4))) float f32x4;

__device__ __forceinline__ float us2f(u16 u){
  union { u32 i; float f; } v; v.i = ((u32)u) << 16; return v.f;
}
__device__ __forceinline__ u16 f2us(float f){
  __bf16 h = (__bf16)f;                       // native RNE convert
  return __builtin_bit_cast(unsigned short, h);
}
__device__ __forceinline__ float lrelu(float v){ return v >= 0.f ? v : 0.001f*v; }

// LDS swizzle for [64 n][256 c] bf16 tile (512B rows), 16B granules
__device__ __forceinline__ u32 swz7(int n, int c){
  return (u32)(n*512 + ((((c>>3) ^ (n&31)) & 31)<<4) + ((c&7)<<1));
}
// LDS swizzle for [col][96 k] bf16 tile padded to 256B rows
__device__ __forceinline__ u32 swz8(int col, int k){
  return (u32)(col*256 + ((((k>>3) ^ (col&15)) & 15)<<4) + ((k&7)<<1));
}

// ---------------- K1: F = w_f.x ; Bm ; AM ; xf ; Ff — 512 thr, 2-way c-split ----------------
__global__ __launch_bounds__(512) void k1_fx(
    const float* __restrict__ x, const float* __restrict__ w_f, const float* __restrict__ w_a2b,
    float* __restrict__ F, float* __restrict__ AM, float* __restrict__ Bm,
    u16* __restrict__ xf, u16* __restrict__ Ff)
{
  __shared__ float wf[CC][KK];   // 16 KB
  __shared__ float wa[CC];       // 1 KB
  __shared__ float pa[256][KK];  // 16 KB partial a0 (half 1)
  __shared__ float ps[256], pm[256], pb[256];   // 3 KB
  int t = threadIdx.x;
  for (int i = t; i < KK*CC; i += 512) wf[i & 255][i >> 8] = w_f[i];
  if (t < CC) wa[t] = w_a2b[t];
  __syncthreads();
  int half = t >> 8, tp = t & 255;
  int pid = blockIdx.x*256 + tp;
  int b = pid / NN;
  int n = pid % NN;
  const float* xp = x + (size_t)b*CC*NN + n;
  float a0[KK];
  #pragma unroll
  for (int k=0;k<KK;k++) a0[k]=0.f;
  float s0=0.f, m0=-3e38f, b0=0.f;
  int nt = n >> 4, lnn = n & 15;
  u16* xfb = xf + ((size_t)(b*576 + nt)*8)*512;   // ks*512 + lane*8 + e  (u16 units)
  int cb0 = half*128;
  #pragma unroll 2
  for (int c8=0; c8<16; ++c8){
    int cb = cb0 + c8*8;
    float v[8];
    #pragma unroll
    for (int e=0;e<8;e++) v[e] = xp[(size_t)(cb+e)*NN];
    union { u16 h[8]; uint4 u; } pk;
    #pragma unroll
    for (int e=0;e<8;e++){
      float vv = v[e];
      s0 += vv;
      m0 = fmaxf(m0, vv);
      b0 = fmaf(wa[cb+e], vv, b0);
      const float* wr = wf[cb+e];
      #pragma unroll
      for (int k=0;k<KK;k++) a0[k] = fmaf(wr[k], vv, a0[k]);
      pk.h[e] = f2us(vv);
    }
    int ks = cb >> 5, lkq = (cb >> 3) & 3;
    *reinterpret_cast<uint4*>(xfb + ((size_t)ks*64 + lkq*16 + lnn)*8) = pk.u;
  }
  if (half){
    #pragma unroll
    for (int k=0;k<KK;k++) pa[tp][k] = a0[k];
    ps[tp] = s0; pm[tp] = m0; pb[tp] = b0;
  }
  __syncthreads();
  if (!half){
    #pragma unroll
    for (int k=0;k<KK;k++) a0[k] += pa[tp][k];
    s0 += ps[tp]; m0 = fmaxf(m0, pm[tp]); b0 += pb[tp];
    float* Fp = F + (size_t)b*KK*NN + n;
    #pragma unroll
    for (int k=0;k<KK;k++) Fp[(size_t)k*NN] = a0[k];
    // Ff: B-frag layout, K=16 padded to 32 (lk 2,3 zero)
    u16* ffb = Ff + (size_t)(b*576 + nt)*512;
    union { u16 h[8]; uint4 u; } pk2;
    #pragma unroll
    for (int lkq=0; lkq<2; lkq++){
      #pragma unroll
      for (int e=0;e<8;e++) pk2.h[e] = f2us(a0[lkq*8+e]);
      *reinterpret_cast<uint4*>(ffb + ((size_t)lkq*16 + lnn)*8) = pk2.u;
    }
    uint4 z; z.x=z.y=z.z=z.w=0u;
    *reinterpret_cast<uint4*>(ffb + ((size_t)2*16 + lnn)*8) = z;
    *reinterpret_cast<uint4*>(ffb + ((size_t)3*16 + lnn)*8) = z;
    AM[(size_t)b*2*NN + n] = s0*(1.f/256.f);
    AM[(size_t)b*2*NN + NN + n] = m0;
    Bm[(size_t)b*NN + n] = lrelu(b0);
  }
}

// ---------------- K2: G[b,k,c] = sum_n F[b,k,n]*x[b,c,n]  (4 c per block) ----------------
__global__ __launch_bounds__(256) void k2_g(
    const float* __restrict__ x, const float* __restrict__ F, float* __restrict__ G)
{
  int b = blockIdx.x >> 6;
  int c0 = (blockIdx.x & 63) * 4;
  int t = threadIdx.x;
  const float* Fp = F + (size_t)b*KK*NN;
  const float* xp = x + ((size_t)b*CC + c0)*NN;
  float acc[KK][4];
  #pragma unroll
  for (int k=0;k<KK;k++){ acc[k][0]=acc[k][1]=acc[k][2]=acc[k][3]=0.f; }
  for (int n = t; n < NN; n += 256){
    float xv0 = xp[n];
    float xv1 = xp[(size_t)NN + n];
    float xv2 = xp[(size_t)2*NN + n];
    float xv3 = xp[(size_t)3*NN + n];
    #pragma unroll
    for (int k=0;k<KK;k++){
      float fv = Fp[(size_t)k*NN + n];
      acc[k][0] = fmaf(fv, xv0, acc[k][0]);
      acc[k][1] = fmaf(fv, xv1, acc[k][1]);
      acc[k][2] = fmaf(fv, xv2, acc[k][2]);
      acc[k][3] = fmaf(fv, xv3, acc[k][3]);
    }
  }
  #pragma unroll
  for (int k=0;k<KK;k++){
    #pragma unroll
    for (int i=0;i<4;i++){
      float v = acc[k][i];
      for (int off=32; off>0; off>>=1) v += __shfl_down(v, off);
      acc[k][i] = v;
    }
  }
  __shared__ float part[4][KK][4];
  int lane = t & 63, wv = t >> 6;
  if (lane == 0){
    #pragma unroll
    for (int k=0;k<KK;k++){ part[wv][k][0]=acc[k][0]; part[wv][k][1]=acc[k][1];
                            part[wv][k][2]=acc[k][2]; part[wv][k][3]=acc[k][3]; }
  }
  __syncthreads();
  if (t < 64){
    int k = t >> 2, i = t & 3;
    float s = part[0][k][i] + part[1][k][i] + part[2][k][i] + part[3][k][i];
    G[((size_t)b*KK + k)*CC + c0 + i] = s;
  }
}

// ---------------- K3: S = softmax_c(G) ; WS = w_beta.S^T packed as MFMA A-frags (K=16 pad 32) ----------------
__global__ __launch_bounds__(256) void k3_smws(
    const float* __restrict__ G, const float* __restrict__ w_beta, u16* __restrict__ wspk)
{
  int b = blockIdx.x, t = threadIdx.x;
  __shared__ float sl[KK][CC];
  for (int k=0;k<KK;k++) sl[k][t] = G[((size_t)b*KK + k)*CC + t];
  __syncthreads();
  int lane = t & 63, wv = t >> 6;
  for (int r=0;r<4;r++){
    int k = wv*4 + r;
    float v0 = sl[k][lane], v1 = sl[k][lane+64], v2 = sl[k][lane+128], v3 = sl[k][lane+192];
    float m = fmaxf(fmaxf(v0,v1), fmaxf(v2,v3));
    for (int off=32; off>0; off>>=1) m = fmaxf(m, __shfl_xor(m, off));
    float e0=__expf(v0-m), e1=__expf(v1-m), e2=__expf(v2-m), e3=__expf(v3-m);
    float s = e0+e1+e2+e3;
    for (int off=32; off>0; off>>=1) s += __shfl_xor(s, off);
    float inv = 1.f/s;
    sl[k][lane]=e0*inv; sl[k][lane+64]=e1*inv; sl[k][lane+128]=e2*inv; sl[k][lane+192]=e3*inv;
  }
  __syncthreads();
  const float* wb = w_beta + (size_t)t*CC;
  float acc[KK];
  #pragma unroll
  for (int k=0;k<KK;k++) acc[k]=0.f;
  for (int c=0;c<CC;c++){
    float w = wb[c];
    #pragma unroll
    for (int k=0;k<KK;k++) acc[k] = fmaf(w, sl[k][c], acc[k]);
  }
  int ot = t >> 4, lo = t & 15;
  union { u16 h[8]; uint4 u; } pk;
  #pragma unroll
  for (int lkq=0; lkq<2; lkq++){
    #pragma unroll
    for (int e=0;e<8;e++) pk.h[e] = f2us(acc[lkq*8+e]);
    *reinterpret_cast<uint4*>(wspk + ((size_t)(b*16 + ot)*64 + lkq*16 + lo)*8) = pk.u;
  }
  uint4 z; z.x=z.y=z.z=z.w=0u;
  *reinterpret_cast<uint4*>(wspk + ((size_t)(b*16 + ot)*64 + 2*16 + lo)*8) = z;
  *reinterpret_cast<uint4*>(wspk + ((size_t)(b*16 + ot)*64 + 3*16 + lo)*8) = z;
}

// ---------------- K5: spatial convs -> F4, Cm ----------------
__global__ __launch_bounds__(256) void k5_conv(
    const float* __restrict__ AM, const float* __restrict__ w1, const float* __restrict__ w3,
    const float* __restrict__ w5, const float* __restrict__ w7, const float* __restrict__ wf2c,
    float* __restrict__ F4, float* __restrict__ Cm)
{
  __shared__ float w3l[18], w5l[50], w7l[98], w1l[2], wcl[4];
  int t = threadIdx.x;
  if (t < 2)  w1l[t] = w1[t];
  if (t < 18) w3l[t] = w3[t];
  if (t < 50) w5l[t] = w5[t];
  if (t < 98) w7l[t] = w7[t];
  if (t < 4)  wcl[t] = wf2c[t];
  __syncthreads();
  int gid = blockIdx.x*256 + t;
  int b = gid / NN, n = gid % NN;
  int h = n / HW, w = n % HW;
  const float* am = AM + (size_t)b*2*NN;
  float a0 = am[n], a1 = am[NN + n];
  float s1v = lrelu(a0*w1l[0] + a1*w1l[1]);
  float s3v=0.f, s5v=0.f, s7v=0.f;
  for (int p=-3;p<=3;p++){
    int hh = h + p;
    if (hh < 0 || hh >= HW) continue;
    for (int q=-3;q<=3;q++){
      int ww = w + q;
      if (ww < 0 || ww >= HW) continue;
      float v0 = am[hh*HW+ww], v1 = am[NN + hh*HW + ww];
      s7v += v0*w7l[(p+3)*7 + (q+3)] + v1*w7l[49 + (p+3)*7 + (q+3)];
      if (p>=-2 && p<=2 && q>=-2 && q<=2)
        s5v += v0*w5l[(p+2)*5 + (q+2)] + v1*w5l[25 + (p+2)*5 + (q+2)];
      if (p>=-1 && p<=1 && q>=-1 && q<=1)
        s3v += v0*w3l[(p+1)*3 + (q+1)] + v1*w3l[9 + (p+1)*3 + (q+1)];
    }
  }
  s3v = lrelu(s3v); s5v = lrelu(s5v); s7v = lrelu(s7v);
  float* f4p = F4 + (size_t)b*4*NN + n;
  f4p[0] = s1v; f4p[NN] = s3v; f4p[2*(size_t)NN] = s5v; f4p[3*(size_t)NN] = s7v;
  Cm[(size_t)b*NN + n] = lrelu(s1v*wcl[0] + s3v*wcl[1] + s5v*wcl[2] + s7v*wcl[3]);
}

// ---------------- K6AB: T rows + softmax + spk pack, 64 blocks (8 b x 8 h-groups of 12) ----------------
__global__ __launch_bounds__(256) void k6ab(
    const float* __restrict__ Bm, const float* __restrict__ Cm, u16* __restrict__ spk)
{
  __shared__ float Cl[NN];        // 36 KB
  __shared__ float Tl[12][96];    // 4.5 KB
  int t = threadIdx.x;
  int b = blockIdx.x >> 3;
  int hg = blockIdx.x & 7;
  for (int i=t; i<NN/4; i+=256)
    *reinterpret_cast<float4*>(&Cl[i*4]) = *reinterpret_cast<const float4*>(&Cm[(size_t)b*NN + i*4]);
  __syncthreads();
  const float* bp = Bm + (size_t)b*NN + (size_t)hg*12*96;
  for (int g=0; g<2; ++g){
    int idx = g*256 + t;
    if (idx < 288){
      int hr = idx/24, k0 = (idx%24)*4;
      const float* brow = bp + hr*96;
      float a0=0.f,a1=0.f,a2=0.f,a3=0.f;
      for (int w2=0; w2<96; ++w2){
        float bv = brow[w2];
        float4 cv = *reinterpret_cast<const float4*>(&Cl[w2*96 + k0]);
        a0=fmaf(bv,cv.x,a0); a1=fmaf(bv,cv.y,a1); a2=fmaf(bv,cv.z,a2); a3=fmaf(bv,cv.w,a3);
      }
      Tl[hr][k0]=a0; Tl[hr][k0+1]=a1; Tl[hr][k0+2]=a2; Tl[hr][k0+3]=a3;
    }
  }
  __syncthreads();
  if (t < 12){
    int h = hg*12 + t;
    float m = -3e38f;
    for (int k=0;k<96;k++) m = fmaxf(m, Tl[t][k]);
    float s = 0.f;
    for (int k=0;k<96;k++) s += __expf(Tl[t][k]-m);
    float inv = 1.f/s;
    int mf = h >> 4;
    for (int g=0; g<12; g++){
      int ks = g >> 2, lk = g & 3;
      union { u16 hh[8]; uint4 u; } pk;
      #pragma unroll
      for (int e=0;e<8;e++) pk.hh[e] = f2us(__expf(Tl[t][g*8+e]-m)*inv);
      *reinterpret_cast<uint4*>(spk + ((size_t)(((b*6 + mf)*3 + ks)*64) + lk*16 + (h&15))*8) = pk.u;
    }
  }
}

// ---------------- KW: pack w_h / w_m / w_hm (256x512) and w_e (256x256) into bf16 A-frag order ----------------
__global__ __launch_bounds__(256) void kw_pack(
    const float* __restrict__ w_h, const float* __restrict__ w_m,
    const float* __restrict__ w_hm, const float* __restrict__ w_e,
    u16* __restrict__ wpk, u16* __restrict__ wpkE)
{
  int gid = blockIdx.x*256 + threadIdx.x;   // 57344
  if (gid < 49152){
    int mat = gid >> 14;
    int r = gid & 16383;
    int ot = r >> 10;
    int ks = (r >> 6) & 15;
    int l  = r & 63;
    const float* W = (mat==0) ? w_h : ((mat==1) ? w_m : w_hm);
    int o = ot*16 + (l & 15);
    int c = ks*32 + (l >> 4)*8;
    const float* src = W + (size_t)o*512 + c;
    union { u16 h[8]; uint4 u; } pk;
    #pragma unroll
    for (int e=0;e<8;e++) pk.h[e] = f2us(src[e]);
    *reinterpret_cast<uint4*>(wpk + (size_t)gid*8) = pk.u;
  } else {
    int r = gid - 49152;                    // 8192 frags for w_e (K=256)
    int ot = r >> 9;
    int ks = (r >> 6) & 7;
    int l  = r & 63;
    int o = ot*16 + (l & 15);
    int c = ks*32 + (l >> 4)*8;
    const float* src = w_e + (size_t)o*256 + c;
    union { u16 h[8]; uint4 u; } pk;
    #pragma unroll
    for (int e=0;e<8;e++) pk.h[e] = f2us(src[e]);
    *reinterpret_cast<uint4*>(wpkE + (size_t)r*8) = pk.u;
  }
}

// ---------------- K7M: WD = w_e . lrelu(w_f2d . F4) — MFMA, M=256 N=64 K=256 per block ----------------
__global__ __launch_bounds__(256) void k7m(
    const float* __restrict__ F4, const float* __restrict__ w_f2d,
    const u16* __restrict__ wpkE, u16* __restrict__ WD)
{
  __shared__ uint4 sm4[2048];               // 32 KB: [64 n][256 c] bf16 swizzled
  char* sm = reinterpret_cast<char*>(sm4);
  int t = threadIdx.x;
  int b = blockIdx.x / 144;
  int n0 = (blockIdx.x % 144) * 64;
  int n = t & 63, cg = t >> 6;
  float f0 = F4[((size_t)b*4+0)*NN + n0 + n];
  float f1 = F4[((size_t)b*4+1)*NN + n0 + n];
  float f2 = F4[((size_t)b*4+2)*NN + n0 + n];
  float f3 = F4[((size_t)b*4+3)*NN + n0 + n];
  for (int c8 = 0; c8 < 8; ++c8){
    int c = cg*64 + c8*8;
    union { u16 h[8]; uint4 u; } pk;
    #pragma unroll
    for (int e=0;e<8;e++){
      const float* wfp = w_f2d + (size_t)(c+e)*4;
      pk.h[e] = f2us(lrelu(fmaf(wfp[0],f0, fmaf(wfp[1],f1, fmaf(wfp[2],f2, wfp[3]*f3)))));
    }
    *reinterpret_cast<uint4*>(sm + swz7(n, c)) = pk.u;
  }
  __syncthreads();
  int w = t >> 6, l = t & 63, ln = l & 15, lk = l >> 4;
  f32x4 acc[4][4];
  #pragma unroll
  for (int i=0;i<4;i++){ acc[i][0]=0.f; acc[i][1]=0.f; acc[i][2]=0.f; acc[i][3]=0.f; }
  for (int ks=0; ks<8; ++ks){
    bf16x8 bfr[4];
    #pragma unroll
    for (int nf=0; nf<4; nf++)
      bfr[nf] = *reinterpret_cast<const bf16x8*>(sm + swz7(nf*16 + ln, ks*32 + lk*8));
    #pragma unroll
    for (int mf=0; mf<4; mf++){
      bf16x8 afr = *reinterpret_cast<const bf16x8*>(wpkE + ((size_t)((w*4+mf)*8 + ks)*64 + l)*8);
      #pragma unroll
      for (int nf=0; nf<4; nf++)
        acc[mf][nf] = __builtin_amdgcn_mfma_f32_16x16x32_bf16(afr, bfr[nf], acc[mf][nf], 0,0,0);
    }
  }
  #pragma unroll
  for (int mf=0; mf<4; mf++){
    #pragma unroll
    for (int nf=0; nf<4; nf++){
      #pragma unroll
      for (int r=0;r<4;r++){
        int o = (w*4+mf)*16 + lk*4 + r;
        WD[((size_t)b*CC + o)*NN + n0 + nf*16 + ln] = f2us(acc[mf][nf][r]);
      }
    }
  }
}

// ---------------- K8M: P = Ssp x WD — MFMA, M=96(h) N=192(2o x 96w) K=96 per block ----------------
__global__ __launch_bounds__(256) void k8m(
    const u16* __restrict__ WD, const u16* __restrict__ spk, u16* __restrict__ P)
{
  __shared__ uint4 sm4[3072];               // 48 KB: [192 col][128 k-pad] bf16 swizzled
  char* sm = reinterpret_cast<char*>(sm4);
  int t = threadIdx.x;
  int b = blockIdx.x >> 7;
  int o0 = (blockIdx.x & 127) * 2;
  for (int it=0; it<9; ++it){
    int s = it*256 + t;                     // 0..2303
    int w16 = s % 12;
    int k   = (s / 12) % 96;
    int oi  = s / 1152;
    union { u16 h[8]; uint4 u; } v;
    v.u = *reinterpret_cast<const uint4*>(WD + ((size_t)b*CC + o0+oi)*NN + k*96 + w16*8);
    #pragma unroll
    for (int e=0;e<8;e++){
      int col = oi*96 + w16*8 + e;
      *reinterpret_cast<u16*>(sm + swz8(col, k)) = v.h[e];
    }
  }
  __syncthreads();
  int w = t >> 6, l = t & 63, ln = l & 15, lk = l >> 4;
  f32x4 acc[6][3];
  #pragma unroll
  for (int i=0;i<6;i++){ acc[i][0]=0.f; acc[i][1]=0.f; acc[i][2]=0.f; }
  for (int ks=0; ks<3; ++ks){
    bf16x8 bfr[3];
    #pragma unroll
    for (int j=0;j<3;j++){
      int col = (w*3 + j)*16 + ln;
      bfr[j] = *reinterpret_cast<const bf16x8*>(sm + swz8(col, ks*32 + lk*8));
    }
    #pragma unroll
    for (int mf=0; mf<6; mf++){
      bf16x8 afr = *reinterpret_cast<const bf16x8*>(spk + ((size_t)(((b*6 + mf)*3 + ks)*64) + l)*8);
      #pragma unroll
      for (int j=0;j<3;j++)
        acc[mf][j] = __builtin_amdgcn_mfma_f32_16x16x32_bf16(afr, bfr[j], acc[mf][j], 0,0,0);
    }
  }
  #pragma unroll
  for (int j=0;j<3;j++){
    int col = (w*3 + j)*16 + ln;
    int oi = (col >= 96) ? 1 : 0;
    int ww = col - 96*oi;
    u16* op = P + ((size_t)b*CC + o0+oi)*NN + ww;
    #pragma unroll
    for (int mf=0; mf<6; mf++){
      #pragma unroll
      for (int r=0;r<4;r++){
        int h = mf*16 + lk*4 + r;
        op[(size_t)h*96] = f2us(acc[mf][j][r]);
      }
    }
  }
}

// ---------------- K8T: o2t = P^T(B-frag) + x — LDS tile transpose + residual ----------------
#define TP 72
__global__ __launch_bounds__(256) void k8t(
    const u16* __restrict__ P, const u16* __restrict__ xf, u16* __restrict__ o2t)
{
  __shared__ u16 tl[256*TP];                // [256 o][72 n-pitch] = 36 KB
  int t = threadIdx.x;
  int b = blockIdx.x / 144;
  int tile = blockIdx.x % 144;
  int n0 = tile * 64;
  for (int it=0; it<8; ++it){
    int o = it*32 + (t >> 3);
    int nb = t & 7;
    uint4 v = *reinterpret_cast<const uint4*>(P + ((size_t)b*CC + o)*NN + n0 + nb*8);
    *reinterpret_cast<uint4*>(&tl[o*TP + nb*8]) = v;
  }
  __syncthreads();
  for (int it=0; it<8; ++it){
    int g = it*256 + t;                     // 0..2047
    int nt_loc = g >> 9;
    int ks = (g >> 6) & 7;
    int lane = g & 63;
    int lkq = lane >> 4, lnn = lane & 15;
    int ob = ks*32 + lkq*8;
    int n_loc = nt_loc*16 + lnn;
    union { u16 h[8]; uint4 u; } gr;
    #pragma unroll
    for (int e=0;e<8;e++) gr.h[e] = tl[(ob+e)*TP + n_loc];
    size_t fo = (((size_t)(b*576 + tile*4 + nt_loc)*8 + ks)*64 + lkq*16 + lnn)*8;
    uint4 xv = *reinterpret_cast<const uint4*>(xf + fo);
    const u32* xp2 = reinterpret_cast<const u32*>(&xv);
    union { u16 h[8]; uint4 u; } res;
    #pragma unroll
    for (int q=0;q<4;q++){
      u32 xw = xp2[q];
      res.h[2*q+0] = f2us(us2f(gr.h[2*q+0]) + us2f((u16)(xw & 0xffffu)));
      res.h[2*q+1] = f2us(us2f(gr.h[2*q+1]) + us2f((u16)(xw >> 16)));
    }
    *reinterpret_cast<uint4*>(o2t + fo) = res.u;
  }
}

// ---------------- K910: out1 -> Hh -> M -> H_M fused, per 64-pixel tile; 512 threads ----------------
__global__ __launch_bounds__(512) void k910(
    const u16* __restrict__ o2t, const u16* __restrict__ xf,
    const u16* __restrict__ Ff, const u16* __restrict__ wspk,
    const u16* __restrict__ wpkH, const u16* __restrict__ wpkM,
    const u16* __restrict__ wpkHM, float* __restrict__ out)
{
  __shared__ uint4 sm4[4096];   // 64 KB: [0,32K)=M, [32K,64K)=out1->Hh
  char* sm = reinterpret_cast<char*>(sm4);
  int t = threadIdx.x;
  int b = blockIdx.x / 144;
  int tile = blockIdx.x % 144;
  int n0 = tile * 64;
  int w = t >> 6, l = t & 63, ln = l & 15, lk = l >> 4;   // w = 0..7 (8 waves)
  // ---- ph0: out1 = WS.F + x (K=16 zero-padded to 32), write to R_B ----
  {
    bf16x8 fb[4];
    #pragma unroll
    for (int nf=0; nf<4; nf++)
      fb[nf] = *reinterpret_cast<const bf16x8*>(Ff + (size_t)(b*576 + tile*4 + nf)*512 + (size_t)l*8);
    #pragma unroll
    for (int mf=0; mf<2; mf++){
      bf16x8 afr = *reinterpret_cast<const bf16x8*>(wspk + ((size_t)(b*16 + w*2 + mf)*64 + l)*8);
      int obase = w*32 + mf*16 + lk*4;
      #pragma unroll
      for (int nf=0; nf<4; nf++){
        f32x4 zz = {0.f,0.f,0.f,0.f};
        f32x4 a1 = __builtin_amdgcn_mfma_f32_16x16x32_bf16(afr, fb[nf], zz, 0,0,0);
        int n = nf*16 + ln;
        int nt = tile*4 + nf;
        u64 xv4 = *reinterpret_cast<const u64*>(
            xf + (((size_t)(b*576 + nt)*8 + (obase>>5))*64 + ((obase>>3)&3)*16 + ln)*8 + (obase&7));
        union { u16 h[4]; u64 u; } pk;
        #pragma unroll
        for (int r=0;r<4;r++)
          pk.h[r] = f2us(a1[r] + us2f((u16)(xv4 >> (16*r))));
        *reinterpret_cast<u64*>(sm + 32768 + swz7(n, obase)) = pk.u;
      }
    }
  }
  __syncthreads();
  f32x4 acc[2][4];
  // ---- ph1: Hh = lrelu(w_h.[out1; out2]) — split loops: LDS half, then global half ----
  #pragma unroll
  for (int i=0;i<2;i++){ acc[i][0]=0.f; acc[i][1]=0.f; acc[i][2]=0.f; acc[i][3]=0.f; }
  #pragma unroll 2
  for (int ks=0; ks<8; ++ks){
    int c = ks*32 + lk*8;
    bf16x8 bfr[4];
    #pragma unroll
    for (int nf=0; nf<4; nf++)
      bfr[nf] = *reinterpret_cast<const bf16x8*>(sm + 32768 + swz7(nf*16 + ln, c));
    #pragma unroll
    for (int mf=0; mf<2; mf++){
      bf16x8 afr = *reinterpret_cast<const bf16x8*>(wpkH + ((size_t)((w*2+mf)*16 + ks)*64 + l)*8);
      #pragma unroll
      for (int nf=0; nf<4; nf++)
        acc[mf][nf] = __builtin_amdgcn_mfma_f32_16x16x32_bf16(afr, bfr[nf], acc[mf][nf], 0,0,0);
    }
  }
  #pragma unroll 2
  for (int ks=8; ks<16; ++ks){
    bf16x8 bfr[4];
    #pragma unroll
    for (int nf=0; nf<4; nf++)
      bfr[nf] = *reinterpret_cast<const bf16x8*>(o2t + (((size_t)(b*576 + tile*4 + nf)*8 + (ks-8))*64 + l)*8);
    #pragma unroll
    for (int mf=0; mf<2; mf++){
      bf16x8 afr = *reinterpret_cast<const bf16x8*>(wpkH + ((size_t)((w*2+mf)*16 + ks)*64 + l)*8);
      #pragma unroll
      for (int nf=0; nf<4; nf++)
        acc[mf][nf] = __builtin_amdgcn_mfma_f32_16x16x32_bf16(afr, bfr[nf], acc[mf][nf], 0,0,0);
    }
  }
  __syncthreads();           // all ph1 reads of R_B complete
  // Hh -> R_B (overwrite out1)
  #pragma unroll
  for (int mf=0; mf<2; mf++){
    int obase = w*32 + mf*16 + lk*4;
    #pragma unroll
    for (int nf=0; nf<4; nf++){
      int n = nf*16 + ln;
      union { u16 h[4]; u64 u; } pk;
      #pragma unroll
      for (int r=0;r<4;r++) pk.h[r] = f2us(lrelu(acc[mf][nf][r]));
      *reinterpret_cast<u64*>(sm + 32768 + swz7(n, obase)) = pk.u;
    }
  }
  __syncthreads();
  // ---- ph2a: M = sigmoid(w_m.[Hh; x]) — split loops ----
  #pragma unroll
  for (int i=0;i<2;i++){ acc[i][0]=0.f; acc[i][1]=0.f; acc[i][2]=0.f; acc[i][3]=0.f; }
  #pragma unroll 2
  for (int ks=0; ks<8; ++ks){
    int c = ks*32 + lk*8;
    bf16x8 bfr[4];
    #pragma unroll
    for (int nf=0; nf<4; nf++)
      bfr[nf] = *reinterpret_cast<const bf16x8*>(sm + 32768 + swz7(nf*16 + ln, c));
    #pragma unroll
    for (int mf=0; mf<2; mf++){
      bf16x8 afr = *reinterpret_cast<const bf16x8*>(wpkM + ((size_t)((w*2+mf)*16 + ks)*64 + l)*8);
      #pragma unroll
      for (int nf=0; nf<4; nf++)
        acc[mf][nf] = __builtin_amdgcn_mfma_f32_16x16x32_bf16(afr, bfr[nf], acc[mf][nf], 0,0,0);
    }
  }
  #pragma unroll 2
  for (int ks=8; ks<16; ++ks){
    bf16x8 bfr[4];
    #pragma unroll
    for (int nf=0; nf<4; nf++)
      bfr[nf] = *reinterpret_cast<const bf16x8*>(xf + (((size_t)(b*576 + tile*4 + nf)*8 + (ks-8))*64 + l)*8);
    #pragma unroll
    for (int mf=0; mf<2; mf++){
      bf16x8 afr = *reinterpret_cast<const bf16x8*>(wpkM + ((size_t)((w*2+mf)*16 + ks)*64 + l)*8);
      #pragma unroll
      for (int nf=0; nf<4; nf++)
        acc[mf][nf] = __builtin_amdgcn_mfma_f32_16x16x32_bf16(afr, bfr[nf], acc[mf][nf], 0,0,0);
    }
  }
  // M -> R_A
  #pragma unroll
  for (int mf=0; mf<2; mf++){
    int obase = w*32 + mf*16 + lk*4;
    #pragma unroll
    for (int nf=0; nf<4; nf++){
      int n = nf*16 + ln;
      union { u16 h[4]; u64 u; } pk;
      #pragma unroll
      for (int r=0;r<4;r++) pk.h[r] = f2us(1.f/(1.f + __expf(-acc[mf][nf][r])));
      *reinterpret_cast<u64*>(sm + swz7(n, obase)) = pk.u;
    }
  }
  __syncthreads();
  // ---- ph2b: out = lrelu(w_hm.[Hh; M]) -> fp32 — split loops (both LDS) ----
  #pragma unroll
  for (int i=0;i<2;i++){ acc[i][0]=0.f; acc[i][1]=0.f; acc[i][2]=0.f; acc[i][3]=0.f; }
  #pragma unroll 2
  for (int ks=0; ks<8; ++ks){
    int c = ks*32 + lk*8;
    bf16x8 bfr[4];
    #pragma unroll
    for (int nf=0; nf<4; nf++)
      bfr[nf] = *reinterpret_cast<const bf16x8*>(sm + 32768 + swz7(nf*16 + ln, c));
    #pragma unroll
    for (int mf=0; mf<2; mf++){
      bf16x8 afr = *reinterpret_cast<const bf16x8*>(wpkHM + ((size_t)((w*2+mf)*16 + ks)*64 + l)*8);
      #pragma unroll
      for (int nf=0; nf<4; nf++)
        acc[mf][nf] = __builtin_amdgcn_mfma_f32_16x16x32_bf16(afr, bfr[nf], acc[mf][nf], 0,0,0);
    }
  }
  #pragma unroll 2
  for (int ks=8; ks<16; ++ks){
    int c = (ks-8)*32 + lk*8;
    bf16x8 bfr[4];
    #pragma unroll
    for (int nf=0; nf<4; nf++)
      bfr[nf] = *reinterpret_cast<const bf16x8*>(sm + swz7(nf*16 + ln, c));
    #pragma unroll
    for (int mf=0; mf<2; mf++){
      bf16x8 afr = *reinterpret_cast<const bf16x8*>(wpkHM + ((size_t)((w*2+mf)*16 + ks)*64 + l)*8);
      #pragma unroll
      for (int nf=0; nf<4; nf++)
        acc[mf][nf] = __builtin_amdgcn_mfma_f32_16x16x32_bf16(afr, bfr[nf], acc[mf][nf], 0,0,0);
    }
  }
  #pragma unroll
  for (int mf=0; mf<2; mf++){
    #pragma unroll
    for (int nf=0; nf<4; nf++){
      #pragma unroll
      for (int r=0;r<4;r++){
        int o = w*32 + mf*16 + lk*4 + r;
        out[((size_t)b*CC + o)*NN + n0 + nf*16 + ln] = lrelu(acc[mf][nf][r]);
      }
    }
  }
}

extern "C" void kernel_launch(void* const* d_in, const int* in_sizes, int n_in,
                              void* d_out, int out_size, void* d_ws, size_t ws_size,
                              hipStream_t stream)
{
  const float* x     = (const float*)d_in[0];
  const float* w_f   = (const float*)d_in[1];
  const float* w_beta= (const float*)d_in[2];
  const float* w1    = (const float*)d_in[3];
  const float* w3    = (const float*)d_in[4];
  const float* w5    = (const float*)d_in[5];
  const float* w7    = (const float*)d_in[6];
  const float* w_a2b = (const float*)d_in[7];
  const float* w_f2c = (const float*)d_in[8];
  const float* w_f2d = (const float*)d_in[9];
  const float* w_e   = (const float*)d_in[10];
  const float* w_h   = (const float*)d_in[11];
  const float* w_m   = (const float*)d_in[12];
  const float* w_hm  = (const float*)d_in[13];

  char* ws = (char*)d_ws;
  size_t off = 0;
  auto alloc = [&](size_t bytes) -> void* {
    void* p = ws + off; off += (bytes + 255) & ~(size_t)255; return p;
  };
  float* F    = (float*)alloc(sizeof(float)*(size_t)BN*KK*NN);
  float* AMb  = (float*)alloc(sizeof(float)*(size_t)BN*2*NN);
  float* Bmv  = (float*)alloc(sizeof(float)*(size_t)BN*NN);
  float* Cmv  = (float*)alloc(sizeof(float)*(size_t)BN*NN);
  float* F4   = (float*)alloc(sizeof(float)*(size_t)BN*4*NN);
  float* G    = (float*)alloc(sizeof(float)*(size_t)BN*KK*CC);
  u16*   spk  = (u16*)alloc(sizeof(u16)*(size_t)BN*NN);           // packed softmax S
  u16*   WD   = (u16*)alloc(sizeof(u16)*(size_t)BN*CC*NN);
  u16*   Pm   = (u16*)alloc(sizeof(u16)*(size_t)BN*CC*NN);        // Ssp x WD, row-major
  u16*   o2t  = (u16*)alloc(sizeof(u16)*(size_t)BN*CC*NN);        // out2 in B-frag layout
  u16*   xf   = (u16*)alloc(sizeof(u16)*(size_t)BN*CC*NN);        // x bf16 B-frag layout
  u16*   Ff   = (u16*)alloc(sizeof(u16)*(size_t)BN*576*512);      // F bf16 B-frags (K pad 32)
  u16*   wpk  = (u16*)alloc(sizeof(u16)*(size_t)3*16384*8);       // packed w_h/w_m/w_hm
  u16*   wpkE = (u16*)alloc(sizeof(u16)*(size_t)8192*8);          // packed w_e
  u16*   wspk = (u16*)alloc(sizeof(u16)*(size_t)BN*16*64*8);      // packed WS A-frags
  (void)ws_size; (void)in_sizes; (void)n_in; (void)out_size;

  u16* wpkH  = wpk;
  u16* wpkM  = wpk + (size_t)16384*8;
  u16* wpkHM = wpk + (size_t)2*16384*8;

  kw_pack <<<224, 256, 0, stream>>>(w_h, w_m, w_hm, w_e, wpk, wpkE);
  k1_fx   <<<288, 512, 0, stream>>>(x, w_f, w_a2b, F, AMb, Bmv, xf, Ff);
  k2_g    <<<512, 256, 0, stream>>>(x, F, G);
  k3_smws <<<8,   256, 0, stream>>>(G, w_beta, wspk);
  k5_conv <<<288, 256, 0, stream>>>(AMb, w1, w3, w5, w7, w_f2c, F4, Cmv);
  k6ab    <<<64,  256, 0, stream>>>(Bmv, Cmv, spk);
  k7m     <<<1152,256, 0, stream>>>(F4, w_f2d, wpkE, WD);
  k8m     <<<1024,256, 0, stream>>>(WD, spk, Pm);
  k8t     <<<1152,256, 0, stream>>>(Pm, xf, o2t);
  k910    <<<1152,512, 0, stream>>>(o2t, xf, Ff, wspk, wpkH, wpkM, wpkHM, (float*)d_out);
}